// Round 13
// baseline (253.287 us; speedup 1.0000x reference)
//
#include <hip/hip_runtime.h>
#include <stdint.h>

// FusedFP4Linear: out = gelu(x @ dequant(w_fp4)^T + bias)
// M=128, K=4096, N=16384. Weights [N, K/2] int32, low byte = two FP4 nibbles
// (hi nibble = even k, lo nibble = odd k).
// R13: R9's split-K/2 GEMM (best measured: ~37us) + FUSED reduction:
// both k-half blocks dump lane-order partial chunks (coalesced f32x4) into
// ws; last-finisher (atomic counter + threadfence, XCD-colocated pair so
// partner chunk is L2-hot) sums partner into live regs and runs the
// scale+bias+GELU epilogue. Removes the 25MB reduce pass + one dispatch.
// Counters zeroed inside convert_x_kernel (stream-ordered).

#define M_DIM 128
#define K_DIM 4096
#define N_DIM 16384
#define BK    64
#define KTH   32               // k-tiles per block (K/2 / 64)
#define NT    512              // 8 waves
#define NBLK_G 512

#define A3OFF(i) ((i)*16384)            // 3 x 16KB A buffers
#define B3OFF(i) (49152 + (i)*8192)     // 3 x 8KB decoded-B buffers
#define LDS_SZ   73728                  // 72KB -> 2 blocks/CU

#define XB_BYTES ((size_t)M_DIM*K_DIM*2)        // 1 MB
#define MN       ((size_t)M_DIM*N_DIM)
#define PART_BYTES (2*MN*4)                     // 16 MB
#define CTR_BYTES  1024                         // 256 counters

typedef __attribute__((ext_vector_type(8))) __bf16 bf16x8;
typedef __attribute__((ext_vector_type(4))) float  f32x4;
typedef unsigned short ushort_t;

__device__ __forceinline__ unsigned f2b_bits(float f) {
  unsigned u = __builtin_bit_cast(unsigned, f);
  u += 0x7FFFu + ((u >> 16) & 1u);   // RNE
  return u >> 16;
}

__global__ __launch_bounds__(256) void convert_x_kernel(
    const float* __restrict__ x, ushort_t* __restrict__ xb,
    int* __restrict__ ctr) {
  if (blockIdx.x == 0) ctr[threadIdx.x] = 0;   // zero 256 tile counters
  int i = (blockIdx.x * blockDim.x + threadIdx.x) * 4;
  float4 v = *(const float4*)(x + i);
  ushort4 p;
  p.x = (ushort_t)f2b_bits(v.x);
  p.y = (ushort_t)f2b_bits(v.y);
  p.z = (ushort_t)f2b_bits(v.z);
  p.w = (ushort_t)f2b_bits(v.w);
  *(ushort4*)(xb + i) = p;
}

__device__ __forceinline__ void gl16(const void* g, void* l) {
  __builtin_amdgcn_global_load_lds(
      (const __attribute__((address_space(1))) void*)g,
      (__attribute__((address_space(3))) void*)l, 16, 0, 0);
}

// 4 packed int32 (low bytes) -> 8 bf16 (k-order: b0.hi, b0.lo, b1.hi, ...)
__device__ __forceinline__ bf16x8 decode8(uint4 p) {
  unsigned u01 = __builtin_amdgcn_perm(p.y, p.x, 0x04000400u);
  unsigned u23 = __builtin_amdgcn_perm(p.w, p.z, 0x04000400u);
  unsigned q   = __builtin_amdgcn_perm(u23, u01, 0x05040100u);  // [x0,y0,z0,w0]
  unsigned e  = (q >> 4) & 0x0F0F0F0Fu;
  unsigned o  = q & 0x0F0F0F0Fu;
  unsigned em = e & 0x07070707u, om = o & 0x07070707u;
  unsigned elo = __builtin_amdgcn_perm(0xC0804000u, 0xC0800000u, em);
  unsigned ehi = __builtin_amdgcn_perm(0x40404040u, 0x3F3F3F00u, em);
  unsigned olo = __builtin_amdgcn_perm(0xC0804000u, 0xC0800000u, om);
  unsigned ohi = __builtin_amdgcn_perm(0x40404040u, 0x3F3F3F00u, om);
  ehi |= (e & 0x08080808u) << 4;
  ohi |= (o & 0x08080808u) << 4;
  unsigned t0 = __builtin_amdgcn_perm(ehi, elo, 0x05010400u);
  unsigned t1 = __builtin_amdgcn_perm(ohi, olo, 0x05010400u);
  unsigned t2 = __builtin_amdgcn_perm(ehi, elo, 0x07030602u);
  unsigned t3 = __builtin_amdgcn_perm(ohi, olo, 0x07030602u);
  uint4 r;
  r.x = __builtin_amdgcn_perm(t1, t0, 0x05040100u);
  r.y = __builtin_amdgcn_perm(t1, t0, 0x07060302u);
  r.z = __builtin_amdgcn_perm(t3, t2, 0x05040100u);
  r.w = __builtin_amdgcn_perm(t3, t2, 0x07060302u);
  return __builtin_bit_cast(bf16x8, r);
}

#define MFMA16(a_, b_, c_) __builtin_amdgcn_mfma_f32_16x16x32_bf16(a_, b_, c_, 0, 0, 0)

__global__ __launch_bounds__(NT, 4) void fp4gemm_split_kernel(
    const ushort_t* __restrict__ xsrc,    // bf16 x [128,4096]
    const int*  __restrict__ wq,          // [N, K/2] packed
    const float* __restrict__ scale,      // [N]
    const float* __restrict__ bias,       // [N]
    float* __restrict__ partial,          // [256 tiles][2][8192] fp32
    int* __restrict__ ctr,                // [256]
    float* __restrict__ out) {            // [M, N]
  __shared__ __align__(16) uint8_t lds[LDS_SZ];
  __shared__ int lastFlag;

  const int t   = threadIdx.x;
  const int w   = t >> 6;                 // wave 0..7
  const int l   = t & 63;
  const int l16 = l & 15;
  const int lq  = l >> 4;
  const int mq  = w >> 1;                 // 0..3: rows mq*32..+31
  const int nh  = w & 1;                  // 0..1: cols nh*32..+31

  // bid -> (xcd = bid&7, nidx = (bid&7)*32 + (bid>>4), khalf = (bid>>3)&1)
  // bijective; both k-halves of an n-tile land on the same XCD.
  const int bid   = blockIdx.x;
  const int nidx  = (bid & 7) * 32 + (bid >> 4);
  const int n0    = nidx * 64;
  const int khalf = (bid >> 3) & 1;
  const int kgB   = khalf * KTH;          // global k-tile base

  // staging geometry: 512 thr x 16B = 8KB = 64 rows x 128B per gl16 round
  const int srow = t >> 3;                // 0..63
  const int scol = (t & 7) * 16;          // byte col 0..112
  const int sswz = (srow & 7) << 4;
  const int scbs = scol ^ sswz;           // pre-swizzled A source col
  const int bwr  = srow * 128 + (scol ^ sswz);   // B decoded LDS write off

  const uint8_t* xb  = (const uint8_t*)xsrc;  // bf16 row = 8192 B
  const uint8_t* wqb = (const uint8_t*)wq;    // int32 row = 8192 B

  uint4 rq0, rq1, rq2, rq3;               // B packed reg slots (mod 4)

#define ISSUE_A(k_, u3_) do { \
  gl16(xb + (size_t)(srow) * 8192 + (size_t)(kgB + (k_)) * 128 + scbs, \
       lds + A3OFF(u3_) + w * 1024); \
  gl16(xb + (size_t)(64 + srow) * 8192 + (size_t)(kgB + (k_)) * 128 + scbs, \
       lds + A3OFF(u3_) + 8192 + w * 1024); \
} while (0)

#define ISSUE_B(k_, s_) do { \
  rq##s_ = *(const uint4*)(wqb + (size_t)(n0 + srow) * 8192 + \
                           (size_t)(kgB + (k_)) * 128 + scol); \
} while (0)

#define DECODE_B(s_, u3_) do { \
  *(bf16x8*)(lds + B3OFF(u3_) + bwr) = decode8(rq##s_); \
} while (0)

#define WAITV(N_) asm volatile("s_waitcnt vmcnt(" #N_ ")" ::: "memory")
#define BARRIER() do { \
  asm volatile("s_waitcnt lgkmcnt(0)" ::: "memory"); \
  __builtin_amdgcn_s_barrier(); \
  __builtin_amdgcn_sched_barrier(0); \
} while (0)

  f32x4 acc00 = {0,0,0,0}, acc01 = {0,0,0,0};
  f32x4 acc10 = {0,0,0,0}, acc11 = {0,0,0,0};

  const int aR0 = (mq * 32 + l16) * 128;       // +2048 for fr=1
  const int bR0 = (nh * 32 + l16) * 128;       // +2048 for c=1
  const int cB  = (lq << 4) ^ ((l16 & 7) << 4);

#define COMPUTE(c3_) do { \
  const uint8_t* Ab_ = lds + A3OFF(c3_); \
  const uint8_t* Bb_ = lds + B3OFF(c3_); \
  _Pragma("unroll") \
  for (int ks_ = 0; ks_ < 2; ++ks_) { \
    const int cS_ = (ks_ << 6) ^ cB; \
    bf16x8 a0_ = *(const bf16x8*)(Ab_ + aR0 + cS_); \
    bf16x8 a1_ = *(const bf16x8*)(Ab_ + aR0 + 2048 + cS_); \
    bf16x8 b0_ = *(const bf16x8*)(Bb_ + bR0 + cS_); \
    bf16x8 b1_ = *(const bf16x8*)(Bb_ + bR0 + 2048 + cS_); \
    acc00 = MFMA16(a0_, b0_, acc00); \
    acc01 = MFMA16(a0_, b1_, acc01); \
    acc10 = MFMA16(a1_, b0_, acc10); \
    acc11 = MFMA16(a1_, b1_, acc11); \
  } \
} while (0)

// Steady body k: WAITV(3) retires A(k) (newer: B(k+5), A(k+1)x2 = exactly 3).
#define BODY_S(k_, s4_, u3_, c3_) do { \
  WAITV(3); \
  BARRIER(); \
  DECODE_B(s4_, u3_); \
  ISSUE_B((k_) + 6, s4_); \
  ISSUE_A((k_) + 2, u3_); \
  COMPUTE(c3_); \
} while (0)

#define GROUP12(k0_) do { \
  BODY_S((k0_)+0, 0,1,2); BODY_S((k0_)+1, 1,2,0); BODY_S((k0_)+2, 2,0,1); \
  BODY_S((k0_)+3, 3,1,2); BODY_S((k0_)+4, 0,2,0); BODY_S((k0_)+5, 1,0,1); \
  BODY_S((k0_)+6, 2,1,2); BODY_S((k0_)+7, 3,2,0); BODY_S((k0_)+8, 0,0,1); \
  BODY_S((k0_)+9, 1,1,2); BODY_S((k0_)+10,2,2,0); BODY_S((k0_)+11,3,0,1); \
} while (0)

  // ---- prologue (FIFO trace: exact) ----
  ISSUE_B(0, 0); ISSUE_B(1, 1); ISSUE_B(2, 2); ISSUE_B(3, 3);   // 4 ops
  ISSUE_A(0, 0); ISSUE_A(1, 1);                                 // 4 ops
  WAITV(4);                      // B0..B3 retired
  DECODE_B(0, 0); DECODE_B(1, 1);
  ISSUE_B(4, 0); ISSUE_B(5, 1);  // outstanding: A0ab A1ab B4 B5 = 6
  // k=0
  WAITV(4); BARRIER();
  DECODE_B(2, 2); ISSUE_B(6, 2); ISSUE_A(2, 2); COMPUTE(0);
  // k=1
  WAITV(5); BARRIER();
  DECODE_B(3, 0); ISSUE_B(7, 3); ISSUE_A(3, 0); COMPUTE(1);
  // ---- steady: k = 2..25 ----
  GROUP12(2);
  GROUP12(14);
  // ---- tail (k = 26..31) ----
  WAITV(3); BARRIER(); DECODE_B(0, 1); ISSUE_A(28, 1); COMPUTE(2);  // k=26
  WAITV(2); BARRIER(); DECODE_B(1, 2); ISSUE_A(29, 2); COMPUTE(0);  // k=27
  WAITV(2); BARRIER(); DECODE_B(2, 0); ISSUE_A(30, 0); COMPUTE(1);  // k=28
  WAITV(2); BARRIER(); DECODE_B(3, 1); ISSUE_A(31, 1); COMPUTE(2);  // k=29
  WAITV(2); BARRIER(); COMPUTE(0);                                  // k=30
  WAITV(0); BARRIER(); COMPUTE(1);                                  // k=31

  // ---- fused split-K reduction: lane-order partial chunks ----
  // chunk layout: partial[nidx*16384 + khalf*8192 + t*16 + frag*4]  (floats)
  {
    float* chunk = partial + (size_t)nidx * 16384 + (size_t)khalf * 8192 +
                   (size_t)t * 16;
    *(f32x4*)(chunk + 0)  = acc00;
    *(f32x4*)(chunk + 4)  = acc01;
    *(f32x4*)(chunk + 8)  = acc10;
    *(f32x4*)(chunk + 12) = acc11;
  }
  __threadfence();                 // release: partial visible before counter
  __syncthreads();                 // all waves' stores issued+fenced
  if (t == 0) lastFlag = (atomicAdd(&ctr[nidx], 1) == 1);
  __syncthreads();
  if (!lastFlag) return;           // first finisher: partial stored, done
  __threadfence();                 // acquire: partner partial now visible
  {
    const float* pchunk = partial + (size_t)nidx * 16384 +
                          (size_t)(khalf ^ 1) * 8192 + (size_t)t * 16;
    acc00 += *(const f32x4*)(pchunk + 0);
    acc01 += *(const f32x4*)(pchunk + 4);
    acc10 += *(const f32x4*)(pchunk + 8);
    acc11 += *(const f32x4*)(pchunk + 12);
  }

  // ---- epilogue: scale, bias, exact GELU ----
#pragma unroll
  for (int c = 0; c < 2; ++c) {
    const int ngc = n0 + nh * 32 + c * 16 + l16;
    const float s  = scale[ngc];
    const float bb = bias[ngc];
    f32x4 v0 = c ? acc01 : acc00;
    f32x4 v1 = c ? acc11 : acc10;
#pragma unroll
    for (int fr = 0; fr < 2; ++fr) {
      f32x4 vv = fr ? v1 : v0;
#pragma unroll
      for (int j = 0; j < 4; ++j) {
        int m = mq * 32 + fr * 16 + lq * 4 + j;
        float y = vv[j] * s + bb;
        float g = 0.5f * y * (1.0f + erff(y * 0.70710678118654752f));
        out[(size_t)m * N_DIM + ngc] = g;
      }
    }
  }
#undef ISSUE_A
#undef ISSUE_B
#undef DECODE_B
#undef WAITV
#undef BARRIER
#undef COMPUTE
#undef BODY_S
#undef GROUP12
}

// Fallback (ws too small): full-K, fp32-x inline, simple 2-buffer pipeline.
__global__ __launch_bounds__(NT) void fp4gemm_fallback_kernel(
    const float* __restrict__ x, const int* __restrict__ wq,
    const float* __restrict__ scale, const float* __restrict__ bias,
    float* __restrict__ out) {
  __shared__ __align__(16) uint8_t lds[49152];
  const int t = threadIdx.x, w = t >> 6, l = t & 63;
  const int l16 = l & 15, lq = l >> 4, mq = w >> 1, nh = w & 1;
  const int n0 = (int)blockIdx.x * 64;
  const int srow = t >> 3, scol = (t & 7) * 16, sswz = (srow & 7) << 4;
  const int bwr = srow * 128 + (scol ^ sswz);
  const uint8_t* wqb = (const uint8_t*)wq;
  f32x4 acc00 = {0,0,0,0}, acc01 = {0,0,0,0};
  f32x4 acc10 = {0,0,0,0}, acc11 = {0,0,0,0};
  const int aR0 = (mq * 32 + l16) * 128;
  const int bR0 = (nh * 32 + l16) * 128;
  const int cB  = (lq << 4) ^ ((l16 & 7) << 4);
  for (int kt = 0; kt < 64; ++kt) {
    __syncthreads();
    int bb = kt & 1;
#pragma unroll
    for (int i = 0; i < 2; ++i) {
      const float* xf = x + (size_t)(i * 64 + srow) * K_DIM + (size_t)kt * 64 + (scol >> 1);
      float4 v0 = *(const float4*)(xf);
      float4 v1 = *(const float4*)(xf + 4);
      uint4 pk = make_uint4(f2b_bits(v0.x) | (f2b_bits(v0.y) << 16),
                            f2b_bits(v0.z) | (f2b_bits(v0.w) << 16),
                            f2b_bits(v1.x) | (f2b_bits(v1.y) << 16),
                            f2b_bits(v1.z) | (f2b_bits(v1.w) << 16));
      *(uint4*)(lds + bb * 16384 + (size_t)(i * 64 + srow) * 128 + (scol ^ sswz)) = pk;
    }
    {
      uint4 pv = *(const uint4*)(wqb + (size_t)(n0 + srow) * 8192 + (size_t)kt * 128 + scol);
      *(bf16x8*)(lds + 32768 + bb * 8192 + bwr) = decode8(pv);
    }
    __syncthreads();
    {
      const uint8_t* Ab_ = lds + bb * 16384;
      const uint8_t* Bb_ = lds + 32768 + bb * 8192;
#pragma unroll
      for (int ks = 0; ks < 2; ++ks) {
        const int cS = (ks << 6) ^ cB;
        bf16x8 a0 = *(const bf16x8*)(Ab_ + aR0 + cS);
        bf16x8 a1 = *(const bf16x8*)(Ab_ + aR0 + 2048 + cS);
        bf16x8 b0 = *(const bf16x8*)(Bb_ + bR0 + cS);
        bf16x8 b1 = *(const bf16x8*)(Bb_ + bR0 + 2048 + cS);
        acc00 = MFMA16(a0, b0, acc00);
        acc01 = MFMA16(a0, b1, acc01);
        acc10 = MFMA16(a1, b0, acc10);
        acc11 = MFMA16(a1, b1, acc11);
      }
    }
  }
#pragma unroll
  for (int c = 0; c < 2; ++c) {
    const int ngc = n0 + nh * 32 + c * 16 + l16;
    const float s = scale[ngc];
    const float bv = bias[ngc];
    f32x4 v0 = c ? acc01 : acc00;
    f32x4 v1 = c ? acc11 : acc10;
#pragma unroll
    for (int fr = 0; fr < 2; ++fr) {
      f32x4 vv = fr ? v1 : v0;
#pragma unroll
      for (int j = 0; j < 4; ++j) {
        int m = mq * 32 + fr * 16 + lq * 4 + j;
        float y = vv[j] * s + bv;
        out[(size_t)m * N_DIM + ngc] =
            0.5f * y * (1.0f + erff(y * 0.70710678118654752f));
      }
    }
  }
}

extern "C" void kernel_launch(void* const* d_in, const int* in_sizes, int n_in,
                              void* d_out, int out_size, void* d_ws, size_t ws_size,
                              hipStream_t stream) {
  const float* x     = (const float*)d_in[0];
  const int*   wq    = (const int*)d_in[1];
  const float* scale = (const float*)d_in[2];
  const float* bias  = (const float*)d_in[3];
  float* out = (float*)d_out;

  if (ws_size >= XB_BYTES + PART_BYTES + CTR_BYTES) {
    ushort_t* xb = (ushort_t*)d_ws;
    float* partial = (float*)((uint8_t*)d_ws + XB_BYTES);
    int* ctr = (int*)((uint8_t*)d_ws + XB_BYTES + PART_BYTES);
    convert_x_kernel<<<(M_DIM * K_DIM) / (256 * 4), 256, 0, stream>>>(x, xb, ctr);
    fp4gemm_split_kernel<<<NBLK_G, NT, 0, stream>>>(xb, wq, scale, bias,
                                                    partial, ctr, out);
  } else {
    fp4gemm_fallback_kernel<<<N_DIM / 64, NT, 0, stream>>>(
        x, wq, scale, bias, out);
  }
}

// Round 14
// 42.649 us; speedup vs baseline: 5.9389x; 5.9389x over previous
//
#include <hip/hip_runtime.h>
#include <stdint.h>

// FusedFP4Linear: out = gelu(x @ dequant(w_fp4)^T + bias)
// M=128, K=4096, N=16384. Weights [N, K/2] int32, low byte = two FP4 nibbles
// (hi nibble = even k, lo nibble = odd k).
// R14: two 8-wave chains per CU via split-M, full K (no partials/fences).
// Block = 64x64 out, 8 waves (2 mh x 4 nq), grid 512, twin-colocated XCD
// swizzle (twin M-blocks share B rows via same-XCD L2). LDS = 4 bufs x
// (8KB A + 8KB B) = 64KB -> exactly 2 blocks/CU. Per tile per thread:
// 1 gl16 (A) + 1 uint4 B-load -> FIFO-retraced counted vmcnt: prologue
// 4/3/4, steady 2, tail 2/1/1/1/1/0. B decode-once at staging (R5-proven).

#define M_DIM 128
#define K_DIM 4096
#define N_DIM 16384
#define NT    512              // 8 waves
#define NBLK  512              // 2 m-blocks x 256 n-tiles

#define ABOFF(b) ((b)*8192)             // 4 x 8KB A bufs (64 rows x 128B)
#define BBOFF(b) (32768 + (b)*8192)     // 4 x 8KB decoded-B bufs
#define LDS_SZ   65536                  // -> 2 blocks/CU

typedef __attribute__((ext_vector_type(8))) __bf16 bf16x8;
typedef __attribute__((ext_vector_type(4))) float  f32x4;
typedef unsigned short ushort_t;

__device__ __forceinline__ unsigned f2b_bits(float f) {
  unsigned u = __builtin_bit_cast(unsigned, f);
  u += 0x7FFFu + ((u >> 16) & 1u);   // RNE
  return u >> 16;
}

__global__ __launch_bounds__(256) void convert_x_kernel(
    const float* __restrict__ x, ushort_t* __restrict__ xb) {
  int i = (blockIdx.x * blockDim.x + threadIdx.x) * 4;
  float4 v = *(const float4*)(x + i);
  ushort4 p;
  p.x = (ushort_t)f2b_bits(v.x);
  p.y = (ushort_t)f2b_bits(v.y);
  p.z = (ushort_t)f2b_bits(v.z);
  p.w = (ushort_t)f2b_bits(v.w);
  *(ushort4*)(xb + i) = p;
}

__device__ __forceinline__ void gl16(const void* g, void* l) {
  __builtin_amdgcn_global_load_lds(
      (const __attribute__((address_space(1))) void*)g,
      (__attribute__((address_space(3))) void*)l, 16, 0, 0);
}

// 4 packed int32 (low bytes) -> 8 bf16 (k-order: b0.hi, b0.lo, b1.hi, ...)
__device__ __forceinline__ bf16x8 decode8(uint4 p) {
  unsigned u01 = __builtin_amdgcn_perm(p.y, p.x, 0x04000400u);
  unsigned u23 = __builtin_amdgcn_perm(p.w, p.z, 0x04000400u);
  unsigned q   = __builtin_amdgcn_perm(u23, u01, 0x05040100u);  // [x0,y0,z0,w0]
  unsigned e  = (q >> 4) & 0x0F0F0F0Fu;
  unsigned o  = q & 0x0F0F0F0Fu;
  unsigned em = e & 0x07070707u, om = o & 0x07070707u;
  unsigned elo = __builtin_amdgcn_perm(0xC0804000u, 0xC0800000u, em);
  unsigned ehi = __builtin_amdgcn_perm(0x40404040u, 0x3F3F3F00u, em);
  unsigned olo = __builtin_amdgcn_perm(0xC0804000u, 0xC0800000u, om);
  unsigned ohi = __builtin_amdgcn_perm(0x40404040u, 0x3F3F3F00u, om);
  ehi |= (e & 0x08080808u) << 4;
  ohi |= (o & 0x08080808u) << 4;
  unsigned t0 = __builtin_amdgcn_perm(ehi, elo, 0x05010400u);
  unsigned t1 = __builtin_amdgcn_perm(ohi, olo, 0x05010400u);
  unsigned t2 = __builtin_amdgcn_perm(ehi, elo, 0x07030602u);
  unsigned t3 = __builtin_amdgcn_perm(ohi, olo, 0x07030602u);
  uint4 r;
  r.x = __builtin_amdgcn_perm(t1, t0, 0x05040100u);
  r.y = __builtin_amdgcn_perm(t1, t0, 0x07060302u);
  r.z = __builtin_amdgcn_perm(t3, t2, 0x05040100u);
  r.w = __builtin_amdgcn_perm(t3, t2, 0x07060302u);
  return __builtin_bit_cast(bf16x8, r);
}

#define MFMA16(a_, b_, c_) __builtin_amdgcn_mfma_f32_16x16x32_bf16(a_, b_, c_, 0, 0, 0)

__global__ __launch_bounds__(NT, 4) void fp4gemm_kernel(
    const ushort_t* __restrict__ xsrc,    // bf16 x [128,4096] (ws)
    const int*  __restrict__ wq,          // [N, K/2] packed
    const float* __restrict__ scale,      // [N]
    const float* __restrict__ bias,       // [N]
    float* __restrict__ out) {            // [M, N]
  __shared__ __align__(16) uint8_t lds[LDS_SZ];

  const int t   = threadIdx.x;
  const int w   = t >> 6;                 // wave 0..7
  const int l   = t & 63;
  const int l16 = l & 15;
  const int lq  = l >> 4;
  const int mh2 = w >> 2;                 // m-half within block: rows mh2*32..+31
  const int nq  = w & 3;                  // n-quad: cols nq*16..+15

  // twin-colocated bijective XCD swizzle (R8-verified):
  //   n0 = ((bid&7)*32 + (bid>>4))*64 ; mblk = (bid>>3)&1
  const int bid  = blockIdx.x;
  const int n0   = ((bid & 7) * 32 + (bid >> 4)) * 64;
  const int mblk = (bid >> 3) & 1;

  // staging geometry: 512 thr x 16B = 8KB = 64 rows x 128B (one round)
  const int srow = t >> 3;                // 0..63
  const int scol = (t & 7) * 16;          // byte col 0..112
  const int sswz = (srow & 7) << 4;
  const int scbs = scol ^ sswz;           // pre-swizzled A source col
  const int bwr  = srow * 128 + (scol ^ sswz);  // B decoded LDS write off

  const uint8_t* xb  = (const uint8_t*)xsrc;  // bf16 row = 8192 B
  const uint8_t* wqb = (const uint8_t*)wq;    // int32 row = 8192 B
  const size_t aRowBase = (size_t)(mblk * 64 + srow) * 8192;

  uint4 rq0, rq1, rq2, rq3;               // B packed reg slots (tile & 3)

#define ISSUE_A1(k_, b_) \
  gl16(xb + aRowBase + (size_t)(k_) * 128 + scbs, lds + ABOFF(b_) + w * 1024)

#define ISSUE_B1(k_, s_) do { \
  rq##s_ = *(const uint4*)(wqb + (size_t)(n0 + srow) * 8192 + \
                           (size_t)(k_) * 128 + scol); \
} while (0)

#define DEC1(s_, b_) do { \
  *(bf16x8*)(lds + BBOFF(b_) + bwr) = decode8(rq##s_); \
} while (0)

#define WAITV(N_) asm volatile("s_waitcnt vmcnt(" #N_ ")" ::: "memory")
#define BARRIER() do { \
  asm volatile("s_waitcnt lgkmcnt(0)" ::: "memory"); \
  __builtin_amdgcn_s_barrier(); \
  __builtin_amdgcn_sched_barrier(0); \
} while (0)

  f32x4 acc0 = {0,0,0,0}, acc1 = {0,0,0,0};   // frags fr=0,1 (rows +0,+16)

  const int aR0 = (mh2 * 32 + l16) * 128;     // fr=1 -> +2048
  const int bR0 = (nq * 16 + l16) * 128;
  const int cB  = (lq << 4) ^ ((l16 & 7) << 4);

#define COMPUTE(b_) do { \
  const uint8_t* Ab_ = lds + ABOFF(b_); \
  const uint8_t* Bb_ = lds + BBOFF(b_); \
  _Pragma("unroll") \
  for (int ks_ = 0; ks_ < 2; ++ks_) { \
    const int cS_ = (ks_ << 6) ^ cB; \
    bf16x8 b0_ = *(const bf16x8*)(Bb_ + bR0 + cS_); \
    bf16x8 a0_ = *(const bf16x8*)(Ab_ + aR0 + cS_); \
    bf16x8 a1_ = *(const bf16x8*)(Ab_ + aR0 + 2048 + cS_); \
    acc0 = MFMA16(a0_, b0_, acc0); \
    acc1 = MFMA16(a1_, b0_, acc1); \
  } \
} while (0)

// Steady body iter k (u_ = (k+2)&3, c_ = k&3):
//   WAITV(2) retires A(k) [outstanding FIFO: B(k+4),A(k),B(k+5),A(k+1)];
//   decode B(k+2)->buf u_; issue B(k+6)->slot u_; stage A(k+2)->buf u_.
#define BODY(k_, u_, c_) do { \
  WAITV(2); \
  BARRIER(); \
  DEC1(u_, u_); \
  ISSUE_B1((k_) + 6, u_); \
  ISSUE_A1((k_) + 2, u_); \
  COMPUTE(c_); \
} while (0)

  // ---- prologue (FIFO-trace exact) ----
  ISSUE_B1(0, 0); ISSUE_B1(1, 1); ISSUE_B1(2, 2); ISSUE_B1(3, 3);
  ISSUE_A1(0, 0); ISSUE_A1(1, 1);
  WAITV(4);                      // B0,B1 retired
  DEC1(0, 0); DEC1(1, 1);
  ISSUE_B1(4, 0); ISSUE_B1(5, 1);   // outstanding: B2,B3,A0,A1,B4,B5
  // iter 0: retire A0 -> newer A1,B4,B5 = 3
  WAITV(3); BARRIER();
  DEC1(2, 2); ISSUE_B1(6, 2); ISSUE_A1(2, 2); COMPUTE(0);
  // iter 1: outstanding A1,B4,B5,B6,A2 -> retire A1 -> newer = 4
  WAITV(4); BARRIER();
  DEC1(3, 3); ISSUE_B1(7, 3); ISSUE_A1(3, 3); COMPUTE(1);
  // ---- steady: k = 2..57 (14 x 4) ----
  for (int j = 0; j < 14; ++j) {
    const int kt = 2 + 4 * j;
    BODY(kt + 0, 0, 2);
    BODY(kt + 1, 1, 3);
    BODY(kt + 2, 2, 0);
    BODY(kt + 3, 3, 1);
  }
  // ---- tail (no B past 63, no A past 63) ----
  WAITV(2); BARRIER(); DEC1(0, 0); ISSUE_A1(60, 0); COMPUTE(2);  // k=58
  WAITV(1); BARRIER(); DEC1(1, 1); ISSUE_A1(61, 1); COMPUTE(3);  // k=59
  WAITV(1); BARRIER(); DEC1(2, 2); ISSUE_A1(62, 2); COMPUTE(0);  // k=60
  WAITV(1); BARRIER(); DEC1(3, 3); ISSUE_A1(63, 3); COMPUTE(1);  // k=61
  WAITV(1); BARRIER(); COMPUTE(2);                               // k=62
  WAITV(0); BARRIER(); COMPUTE(3);                               // k=63

  // ---- epilogue: scale, bias, exact GELU ----
  {
    const int ngc = n0 + nq * 16 + l16;
    const float s  = scale[ngc];
    const float bb = bias[ngc];
#pragma unroll
    for (int fr = 0; fr < 2; ++fr) {
      f32x4 vv = fr ? acc1 : acc0;
#pragma unroll
      for (int j = 0; j < 4; ++j) {
        int m = mblk * 64 + mh2 * 32 + fr * 16 + lq * 4 + j;
        float y = vv[j] * s + bb;
        float g = 0.5f * y * (1.0f + erff(y * 0.70710678118654752f));
        out[(size_t)m * N_DIM + ngc] = g;
      }
    }
  }
#undef ISSUE_A1
#undef ISSUE_B1
#undef DEC1
#undef WAITV
#undef BARRIER
#undef COMPUTE
#undef BODY
}

// Fallback (ws too small): full-K, fp32-x inline, simple 2-buffer pipeline.
__global__ __launch_bounds__(512) void fp4gemm_fallback_kernel(
    const float* __restrict__ x, const int* __restrict__ wq,
    const float* __restrict__ scale, const float* __restrict__ bias,
    float* __restrict__ out) {
  __shared__ __align__(16) uint8_t lds[49152];
  const int t = threadIdx.x, w = t >> 6, l = t & 63;
  const int l16 = l & 15, lq = l >> 4, mq = w >> 1, nh = w & 1;
  const int n0 = (int)blockIdx.x * 64;
  const int srow = t >> 3, scol = (t & 7) * 16, sswz = (srow & 7) << 4;
  const int bwr = srow * 128 + (scol ^ sswz);
  const uint8_t* wqb = (const uint8_t*)wq;
  f32x4 acc00 = {0,0,0,0}, acc01 = {0,0,0,0};
  f32x4 acc10 = {0,0,0,0}, acc11 = {0,0,0,0};
  const int aR0 = (mq * 32 + l16) * 128;
  const int bR0 = (nh * 32 + l16) * 128;
  const int cB  = (lq << 4) ^ ((l16 & 7) << 4);
  for (int kt = 0; kt < 64; ++kt) {
    __syncthreads();
    int bb = kt & 1;
#pragma unroll
    for (int i = 0; i < 2; ++i) {
      const float* xf = x + (size_t)(i * 64 + srow) * K_DIM + (size_t)kt * 64 + (scol >> 1);
      float4 v0 = *(const float4*)(xf);
      float4 v1 = *(const float4*)(xf + 4);
      uint4 pk = make_uint4(f2b_bits(v0.x) | (f2b_bits(v0.y) << 16),
                            f2b_bits(v0.z) | (f2b_bits(v0.w) << 16),
                            f2b_bits(v1.x) | (f2b_bits(v1.y) << 16),
                            f2b_bits(v1.z) | (f2b_bits(v1.w) << 16));
      *(uint4*)(lds + bb * 16384 + (size_t)(i * 64 + srow) * 128 + (scol ^ sswz)) = pk;
    }
    {
      uint4 pv = *(const uint4*)(wqb + (size_t)(n0 + srow) * 8192 + (size_t)kt * 128 + scol);
      *(bf16x8*)(lds + 32768 + bb * 8192 + bwr) = decode8(pv);
    }
    __syncthreads();
    {
      const uint8_t* Ab_ = lds + bb * 16384;
      const uint8_t* Bb_ = lds + 32768 + bb * 8192;
#pragma unroll
      for (int ks = 0; ks < 2; ++ks) {
        const int cS = (ks << 6) ^ cB;
        bf16x8 a0 = *(const bf16x8*)(Ab_ + aR0 + cS);
        bf16x8 a1 = *(const bf16x8*)(Ab_ + aR0 + 2048 + cS);
        bf16x8 b0 = *(const bf16x8*)(Bb_ + bR0 + cS);
        bf16x8 b1 = *(const bf16x8*)(Bb_ + bR0 + 2048 + cS);
        acc00 = MFMA16(a0, b0, acc00);
        acc01 = MFMA16(a0, b1, acc01);
        acc10 = MFMA16(a1, b0, acc10);
        acc11 = MFMA16(a1, b1, acc11);
      }
    }
  }
#pragma unroll
  for (int c = 0; c < 2; ++c) {
    const int ngc = n0 + nh * 32 + c * 16 + l16;
    const float s = scale[ngc];
    const float bv = bias[ngc];
    f32x4 v0 = c ? acc01 : acc00;
    f32x4 v1 = c ? acc11 : acc10;
#pragma unroll
    for (int fr = 0; fr < 2; ++fr) {
      f32x4 vv = fr ? v1 : v0;
#pragma unroll
      for (int j = 0; j < 4; ++j) {
        int m = mq * 32 + fr * 16 + lq * 4 + j;
        float y = vv[j] * s + bv;
        out[(size_t)m * N_DIM + ngc] =
            0.5f * y * (1.0f + erff(y * 0.70710678118654752f));
      }
    }
  }
}

extern "C" void kernel_launch(void* const* d_in, const int* in_sizes, int n_in,
                              void* d_out, int out_size, void* d_ws, size_t ws_size,
                              hipStream_t stream) {
  const float* x     = (const float*)d_in[0];
  const int*   wq    = (const int*)d_in[1];
  const float* scale = (const float*)d_in[2];
  const float* bias  = (const float*)d_in[3];
  float* out = (float*)d_out;

  const size_t xb_bytes = (size_t)M_DIM * K_DIM * 2;   // 1 MB
  if (ws_size >= xb_bytes) {
    ushort_t* xb = (ushort_t*)d_ws;
    convert_x_kernel<<<(M_DIM * K_DIM) / (256 * 4), 256, 0, stream>>>(x, xb);
    fp4gemm_kernel<<<NBLK, NT, 0, stream>>>(xb, wq, scale, bias, out);
  } else {
    fp4gemm_fallback_kernel<<<N_DIM / 64, 512, 0, stream>>>(
        x, wq, scale, bias, out);
  }
}

// Round 15
// 41.608 us; speedup vs baseline: 6.0875x; 1.0250x over previous
//
#include <hip/hip_runtime.h>
#include <stdint.h>

// FusedFP4Linear: out = gelu(x @ dequant(w_fp4)^T + bias)
// M=128, K=4096, N=16384. Weights [N, K/2] int32, low byte = two FP4 nibbles
// (hi nibble = even k, lo nibble = odd k).
// FINAL (revert to R7, best measured 41.96us): k-split waves. 8 waves =
// 4 output positions (2m x 2n of 64x32) x 2 k-halves; each wave computes a
// 32-wide k-slice per tile (6 ds_read_b128 + 8 MFMA). Cross-wave acc reduce
// through LDS once at the end. A staged via global_load_lds (pre-swizzled
// source), B global->reg->v_perm-decode-once->LDS. NBUF=4-ish (A x4 / B x4
// within 96KB), counted vmcnt (steady outstanding 9, vmcnt(6)).

#define M_DIM 128
#define K_DIM 4096
#define N_DIM 16384
#define BN    64
#define BK    64
#define NK    (K_DIM/BK)       // 64
#define NT    512              // 8 waves
#define NBLK  (N_DIM/BN)       // 256

#define A_BYTES 16384          // 128 rows x 128B bf16
#define B_BYTES 8192           // 64 rows x 128B bf16 (decoded)
#define NBUF    4
#define AOFF(b) ((b)*A_BYTES)
#define BOFF(b) (NBUF*A_BYTES + (b)*B_BYTES)
#define LDS_SZ  (NBUF*(A_BYTES+B_BYTES))   // 98304

typedef __attribute__((ext_vector_type(8))) __bf16 bf16x8;
typedef __attribute__((ext_vector_type(4))) float  f32x4;
typedef unsigned short ushort_t;

__device__ __forceinline__ unsigned f2b_bits(float f) {
  unsigned u = __builtin_bit_cast(unsigned, f);
  u += 0x7FFFu + ((u >> 16) & 1u);   // RNE
  return u >> 16;
}

__global__ __launch_bounds__(256) void convert_x_kernel(
    const float* __restrict__ x, ushort_t* __restrict__ xb) {
  int i = (blockIdx.x * blockDim.x + threadIdx.x) * 4;
  float4 v = *(const float4*)(x + i);
  ushort4 p;
  p.x = (ushort_t)f2b_bits(v.x);
  p.y = (ushort_t)f2b_bits(v.y);
  p.z = (ushort_t)f2b_bits(v.z);
  p.w = (ushort_t)f2b_bits(v.w);
  *(ushort4*)(xb + i) = p;
}

__device__ __forceinline__ void gl16(const void* g, void* l) {
  __builtin_amdgcn_global_load_lds(
      (const __attribute__((address_space(1))) void*)g,
      (__attribute__((address_space(3))) void*)l, 16, 0, 0);
}

// 4 packed int32 (low bytes) -> 8 bf16 (k-order: b0.hi, b0.lo, b1.hi, ...)
__device__ __forceinline__ bf16x8 decode8(uint4 p) {
  unsigned u01 = __builtin_amdgcn_perm(p.y, p.x, 0x04000400u);
  unsigned u23 = __builtin_amdgcn_perm(p.w, p.z, 0x04000400u);
  unsigned q   = __builtin_amdgcn_perm(u23, u01, 0x05040100u);  // [x0,y0,z0,w0]
  unsigned e  = (q >> 4) & 0x0F0F0F0Fu;    // even-k nibbles
  unsigned o  = q & 0x0F0F0F0Fu;           // odd-k nibbles
  unsigned em = e & 0x07070707u, om = o & 0x07070707u;
  unsigned elo = __builtin_amdgcn_perm(0xC0804000u, 0xC0800000u, em);
  unsigned ehi = __builtin_amdgcn_perm(0x40404040u, 0x3F3F3F00u, em);
  unsigned olo = __builtin_amdgcn_perm(0xC0804000u, 0xC0800000u, om);
  unsigned ohi = __builtin_amdgcn_perm(0x40404040u, 0x3F3F3F00u, om);
  ehi |= (e & 0x08080808u) << 4;           // sign -> bit7 of high byte
  ohi |= (o & 0x08080808u) << 4;
  unsigned t0 = __builtin_amdgcn_perm(ehi, elo, 0x05010400u);
  unsigned t1 = __builtin_amdgcn_perm(ohi, olo, 0x05010400u);
  unsigned t2 = __builtin_amdgcn_perm(ehi, elo, 0x07030602u);
  unsigned t3 = __builtin_amdgcn_perm(ohi, olo, 0x07030602u);
  uint4 r;
  r.x = __builtin_amdgcn_perm(t1, t0, 0x05040100u);
  r.y = __builtin_amdgcn_perm(t1, t0, 0x07060302u);
  r.z = __builtin_amdgcn_perm(t3, t2, 0x05040100u);
  r.w = __builtin_amdgcn_perm(t3, t2, 0x07060302u);
  return __builtin_bit_cast(bf16x8, r);
}

#define MFMA16(a_, b_, c_) __builtin_amdgcn_mfma_f32_16x16x32_bf16(a_, b_, c_, 0, 0, 0)

template<bool USE_XB>
__global__ __launch_bounds__(NT) void fp4gemm_kernel(
    const void* __restrict__ xsrc,        // bf16 xb (ws) or fp32 x
    const int*  __restrict__ wq,          // [N, K/2] packed
    const float* __restrict__ scale,      // [N]
    const float* __restrict__ bias,       // [N]
    float* __restrict__ out) {            // [M, N]
  __shared__ __align__(16) uint8_t lds[LDS_SZ];

  const int t   = threadIdx.x;
  const int w   = t >> 6;                 // wave 0..7
  const int l   = t & 63;
  const int l16 = l & 15;
  const int lq  = l >> 4;
  const int kh  = w >> 2;                 // k-half 0..1 (ks slice)
  const int mh  = (w >> 1) & 1;           // m-half: rows mh*64..+63
  const int nh  = w & 1;                  // n-half: cols nh*32..+31

  // XCD-aware bijective swizzle (256 % 8 == 0)
  const int bid = blockIdx.x;
  const int n0  = ((bid & 7) * (NBLK / 8) + (bid >> 3)) * BN;

  // staging geometry: 512 threads x 16B = 8KB = 64 rows x 128B
  const int srow = t >> 3;                // 0..63
  const int scol = (t & 7) * 16;          // byte col 0..112
  const int sswz = (srow & 7) << 4;
  const int scbs = scol ^ sswz;           // swizzled source col (gl16 path)
  const int bwr  = srow * 128 + (scol ^ sswz);  // B LDS write offset

  const uint8_t* xb  = (const uint8_t*)xsrc;  // bf16 row = 8192 B
  const uint8_t* wqb = (const uint8_t*)wq;    // int32 row = 8192 B

  uint4 rq0, rq1, rq2, rq3;               // B packed reg slots

#define ISSUE_A(k_, b_) do { \
  gl16(xb + (size_t)(srow) * 8192 + (size_t)(k_) * 128 + scbs, \
       lds + AOFF(b_) + w * 1024); \
  gl16(xb + (size_t)(64 + srow) * 8192 + (size_t)(k_) * 128 + scbs, \
       lds + AOFF(b_) + 8192 + w * 1024); \
} while (0)

#define ISSUE_B(k_, s_) do { \
  rq##s_ = *(const uint4*)(wqb + (size_t)(n0 + srow) * 8192 + \
                           (size_t)(k_) * 128 + scol); \
} while (0)

#define DECODE_B(s_, b_) do { \
  *(bf16x8*)(lds + BOFF(b_) + bwr) = decode8(rq##s_); \
} while (0)

#define WAITV(N_) asm volatile("s_waitcnt vmcnt(" #N_ ")" ::: "memory")
#define BARRIER() do { \
  asm volatile("s_waitcnt lgkmcnt(0)" ::: "memory"); \
  __builtin_amdgcn_s_barrier(); \
  __builtin_amdgcn_sched_barrier(0); \
} while (0)

  f32x4 acc[4][2] = {{{0,0,0,0},{0,0,0,0}},{{0,0,0,0},{0,0,0,0}},
                     {{0,0,0,0},{0,0,0,0}},{{0,0,0,0},{0,0,0,0}}};

  // read-side col offset: k-base (lq*16 + kh*64) XOR row-swizzle
  const int cS  = ((lq << 4) + (kh << 6)) ^ ((l16 & 7) << 4);
  const int aR0 = (mh * 64 + l16) * 128;       // + r*2048
  const int bR0 = (nh * 32 + l16) * 128;       // + c*2048

#define COMPUTE(b_) do { \
  const uint8_t* Ab_ = lds + AOFF(b_); \
  const uint8_t* Bb_ = lds + BOFF(b_); \
  bf16x8 bf0_ = *(const bf16x8*)(Bb_ + bR0 + cS); \
  bf16x8 bf1_ = *(const bf16x8*)(Bb_ + bR0 + 2048 + cS); \
  _Pragma("unroll") \
  for (int r_ = 0; r_ < 4; ++r_) { \
    bf16x8 af_ = *(const bf16x8*)(Ab_ + aR0 + r_ * 2048 + cS); \
    acc[r_][0] = MFMA16(af_, bf0_, acc[r_][0]); \
    acc[r_][1] = MFMA16(af_, bf1_, acc[r_][1]); \
  } \
} while (0)

// BODY(k): wait A(k); barrier; decode B(k+2) -> LDS buf u=(k+2)&3;
// issue B(k+6) -> slot u; issue A(k+3) -> buf ab=(k+3)&3; compute tile k.
#define BODY(k_, u_, ab_, cb_) do { \
  WAITV(6); \
  BARRIER(); \
  DECODE_B(u_, u_); \
  ISSUE_B((k_) + 6, u_); \
  ISSUE_A((k_) + 3, ab_); \
  COMPUTE(cb_); \
} while (0)

  if constexpr (USE_XB) {
    // ---- prologue ----  (FIFO trace verified; steady outstanding = 9)
    ISSUE_B(0, 0); ISSUE_B(1, 1); ISSUE_B(2, 2); ISSUE_B(3, 3);
    ISSUE_A(0, 0); ISSUE_A(1, 1); ISSUE_A(2, 2);
    WAITV(6);                       // B0..B3 landed
    DECODE_B(0, 0); DECODE_B(1, 1);
    ISSUE_B(4, 0); ISSUE_B(5, 1);
    // kt = 0
    WAITV(6); BARRIER();
    DECODE_B(2, 2); ISSUE_B(6, 2); ISSUE_A(3, 3); COMPUTE(0);
    // kt = 1
    WAITV(6); BARRIER();
    DECODE_B(3, 3); ISSUE_B(7, 3); ISSUE_A(4, 0); COMPUTE(1);
    // ---- main loop: kt = 2..57 ----
    for (int j = 0; j < 14; ++j) {
      BODY(2 + 4 * j, 0, 1, 2);
      BODY(3 + 4 * j, 1, 2, 3);
      BODY(4 + 4 * j, 2, 3, 0);
      BODY(5 + 4 * j, 3, 0, 1);
    }
    // ---- tail ----
    WAITV(6); BARRIER(); DECODE_B(0, 0); ISSUE_A(61, 1); COMPUTE(2);  // kt=58
    WAITV(5); BARRIER(); DECODE_B(1, 1); ISSUE_A(62, 2); COMPUTE(3);  // kt=59
    WAITV(4); BARRIER(); DECODE_B(2, 2); ISSUE_A(63, 3); COMPUTE(0);  // kt=60
    WAITV(4); BARRIER(); DECODE_B(3, 3); COMPUTE(1);                  // kt=61
    WAITV(2); BARRIER(); COMPUTE(2);                                  // kt=62
    WAITV(0); BARRIER(); COMPUTE(3);                                  // kt=63
  } else {
    // fallback (ws too small): simple 2-buffer __syncthreads pipeline
    for (int kt = 0; kt < NK; ++kt) {
      __syncthreads();
#pragma unroll
      for (int i = 0; i < 2; ++i) {
        const float* xf = (const float*)xsrc +
            (size_t)(i * 64 + srow) * K_DIM + (size_t)kt * BK + (scol >> 1);
        float4 v0 = *(const float4*)(xf);
        float4 v1 = *(const float4*)(xf + 4);
        uint4 pk = make_uint4(f2b_bits(v0.x) | (f2b_bits(v0.y) << 16),
                              f2b_bits(v0.z) | (f2b_bits(v0.w) << 16),
                              f2b_bits(v1.x) | (f2b_bits(v1.y) << 16),
                              f2b_bits(v1.z) | (f2b_bits(v1.w) << 16));
        *(uint4*)(lds + AOFF(kt & 1) + (size_t)(i * 64 + srow) * 128 +
                  (scol ^ sswz)) = pk;
      }
      {
        uint4 pv = *(const uint4*)(wqb + (size_t)(n0 + srow) * 8192 +
                                   (size_t)kt * 128 + scol);
        *(bf16x8*)(lds + BOFF(kt & 1) + bwr) = decode8(pv);
      }
      __syncthreads();
      COMPUTE(kt & 1);
    }
  }

  // ---- cross-wave k-reduce (pairs w, w+4 share output position w&3) ----
  __syncthreads();                        // all LDS buffer reads done
  {
    uint8_t* red = lds;                   // 4 pos x 8KB = 32KB (reuse)
    const int pos = w & 3;
    if (w >= 4) {
#pragma unroll
      for (int r = 0; r < 4; ++r)
#pragma unroll
        for (int c = 0; c < 2; ++c)
          *(f32x4*)(red + pos * 8192 + (r * 2 + c) * 1024 + l * 16) = acc[r][c];
    }
    __syncthreads();
    if (w < 4) {
#pragma unroll
      for (int r = 0; r < 4; ++r)
#pragma unroll
        for (int c = 0; c < 2; ++c)
          acc[r][c] += *(const f32x4*)(red + pos * 8192 + (r * 2 + c) * 1024 + l * 16);

      // ---- epilogue: scale, bias, exact GELU ----
#pragma unroll
      for (int c = 0; c < 2; ++c) {
        const int ngc = n0 + nh * 32 + c * 16 + l16;
        const float s  = scale[ngc];
        const float bb = bias[ngc];
#pragma unroll
        for (int r = 0; r < 4; ++r) {
#pragma unroll
          for (int j = 0; j < 4; ++j) {
            int m = mh * 64 + r * 16 + lq * 4 + j;
            float y = acc[r][c][j] * s + bb;
            float g = 0.5f * y * (1.0f + erff(y * 0.70710678118654752f));
            out[(size_t)m * N_DIM + ngc] = g;
          }
        }
      }
    }
  }
#undef ISSUE_A
#undef ISSUE_B
#undef DECODE_B
#undef WAITV
#undef BARRIER
#undef COMPUTE
#undef BODY
}

extern "C" void kernel_launch(void* const* d_in, const int* in_sizes, int n_in,
                              void* d_out, int out_size, void* d_ws, size_t ws_size,
                              hipStream_t stream) {
  const float* x     = (const float*)d_in[0];
  const int*   wq    = (const int*)d_in[1];
  const float* scale = (const float*)d_in[2];
  const float* bias  = (const float*)d_in[3];
  float* out = (float*)d_out;

  const size_t xb_bytes = (size_t)M_DIM * K_DIM * 2;   // 1 MB
  if (ws_size >= xb_bytes) {
    ushort_t* xb = (ushort_t*)d_ws;
    convert_x_kernel<<<(M_DIM * K_DIM) / (256 * 4), 256, 0, stream>>>(x, xb);
    fp4gemm_kernel<true><<<NBLK, NT, 0, stream>>>(xb, wq, scale, bias, out);
  } else {
    fp4gemm_kernel<false><<<NBLK, NT, 0, stream>>>(x, wq, scale, bias, out);
  }
}